// Round 9
// baseline (21659.885 us; speedup 1.0000x reference)
//
#include <hip/hip_runtime.h>
#include <hip/hip_bf16.h>
#include <math.h>

// ---------------- problem constants ----------------
#define B_        4096
#define ENC_STEPS 49     // SRC-1
#define TGT_      25
#define R_        1024
#define H_        67
#define I_        82
#define IP_       96     // input padded to multiple of 32
#define IP2_      192    // split-bf16 (hi|lo) doubled K
#define NG_       3072   // 3*R
#define FCN_      128    // fc output padded 67 -> 128
#define K2_       2048   // 2*R

typedef unsigned short u16;
typedef __attribute__((ext_vector_type(8))) short bf16x8_t;
typedef __attribute__((ext_vector_type(4))) float f32x4_t;

// ---------------- helpers ----------------
__device__ __forceinline__ float bf2f(u16 h) {
    union { unsigned int u; float f; } v; v.u = ((unsigned int)h) << 16; return v.f;
}
__device__ __forceinline__ u16 f2bf(float f) {
    union { unsigned int u; float f; } v; v.f = f;
    unsigned int u = v.u;
    u += 0x7fffu + ((u >> 16) & 1u);   // RNE
    return (u16)(u >> 16);
}
__device__ __forceinline__ float sigmf(float x) { return 1.f / (1.f + __expf(-x)); }
__device__ __forceinline__ float tanhfast(float x) { return 1.f - 2.f / (__expf(2.f * x) + 1.f); }

// async global->LDS, 16B per lane. LDS dest must be wave-uniform base + lane*16,
// which our chunk mappings guarantee (lane-contiguous linear dest).
__device__ __forceinline__ void g2l16(const u16* g, u16* l) {
    __builtin_amdgcn_global_load_lds(
        (const __attribute__((address_space(1))) unsigned int*)(const void*)g,
        (__attribute__((address_space(3))) unsigned int*)(void*)l,
        16, 0, 0);
}

// ---------------- weight prep ----------------
__global__ void cast_bf16_kernel(const float* __restrict__ s, u16* __restrict__ d, int n) {
    int i = blockIdx.x * 256 + threadIdx.x;
    if (i < n) d[i] = f2bf(s[i]);
}
// Wi1 [3072,82] -> [3072,192] bf16: cols 0..95 padded Wi1, cols 96..191 duplicate (hi|lo split)
__global__ void pad_wi1_dup_kernel(const float* __restrict__ s, u16* __restrict__ d) {
    int i = blockIdx.x * 256 + threadIdx.x;
    if (i >= NG_ * IP2_) return;
    int r = i / IP2_, c = i % IP2_;
    int cc = (c < IP_) ? c : c - IP_;
    d[i] = (cc < I_) ? f2bf(s[r * I_ + cc]) : (u16)0;
}
// Wfc [67,2048] -> [128,2048] bf16, zero-padded N rows
__global__ void pad_wfc_kernel(const float* __restrict__ s, u16* __restrict__ d) {
    int i = blockIdx.x * 256 + threadIdx.x;
    if (i >= FCN_ * K2_) return;
    int r = i / K2_, c = i % K2_;
    d[i] = (r < H_) ? f2bf(s[r * K2_ + c]) : (u16)0;
}

// all encoder inputs -> xall bf16 [ENC][B][192] (hi|lo split), one launch
__global__ void pad_all_x_kernel(const float* __restrict__ enc, u16* __restrict__ xall) {
    int i = blockIdx.x * 256 + threadIdx.x;
    if (i >= B_ * ENC_STEPS * IP_) return;
    int c = i % IP_;
    int t = (i / IP_) % ENC_STEPS;
    int b = i / (IP_ * ENC_STEPS);
    float v = (c < I_) ? enc[((size_t)b * ENC_STEPS + t) * I_ + c] : 0.f;
    u16 hi = f2bf(v);
    u16 lo = f2bf(v - bf2f(hi));
    size_t base = ((size_t)t * B_ + b) * IP2_;
    xall[base + c]       = hi;
    xall[base + IP_ + c] = lo;
}

// decoder inp for t==0 (later steps are fused into fc_finish)
__global__ void build_inp_kernel(const float* __restrict__ prev, int pstride,
                                 const float* __restrict__ dec, int t,
                                 u16* __restrict__ xpad) {
    int i = blockIdx.x * 256 + threadIdx.x;
    if (i >= B_ * IP_) return;
    int b = i / IP_, c = i % IP_;
    float v = 0.f;
    if (c < H_)      v = prev[(size_t)b * pstride + c];
    else if (c < I_) v = dec[((size_t)b * TGT_ + t) * I_ + c];
    u16 hi = f2bf(v);
    u16 lo = f2bf(v - bf2f(hi));
    xpad[(size_t)b * IP2_ + c]       = hi;
    xpad[(size_t)b * IP2_ + IP_ + c] = lo;
}

// ---------------- fused GRU step (one layer) ----------------
// Tile: 128 batch rows x 64 R-cols x 3 gates; 256 threads = 4 waves (2M x 2N);
// 2 blocks/CU. BK=64, double-buffered LDS (80 KB), R8's verified counted-vmcnt
// stage discipline. NEW: m201-style PHASE SCHEDULE inside each tile — 6 phases
// (per kk half: r/z/n gate clusters), each {ds_read subtile -> s_barrier ->
// lgkmcnt(0) -> setprio(1) -> 8 MFMA -> setprio(0) -> s_barrier}. The phase
// barriers stagger waves so one wave's LDS reads overlap another's MFMAs
// (the T3 regime gate that makes T2/T5 pay). Staging addresses precomputed
// once (loop-invariant) to cut per-stage VALU.
// LDS rows are 128 B -> XOR swizzle pos^=(row&7) on BOTH the global source
// chunk (linear LDS dest, rule-21) and the ds_read offset (0 conflicts R2-R8).
template<int KX>
__global__ __launch_bounds__(256, 2) void gru_step_kernel(
    const u16* __restrict__ Ax, int ldax,       // [B, ldax] bf16 input
    const u16* __restrict__ Wx,                 // [3R, KX] bf16
    const u16* __restrict__ Ah, int ldah,       // [B, ldah] bf16 state (cur)
    const u16* __restrict__ Wh,                 // [3R, 1024] bf16
    const float* __restrict__ bi, const float* __restrict__ bh,
    float* __restrict__ hf,                     // [B, R] fp32 state, in/out (in-place per-tile)
    u16* __restrict__ hout)                     // bf16 state out (nxt buffer), row stride K2_
{
    __shared__ __align__(16) u16 As[2][128 * 64];       // 2 x 16 KB
    __shared__ __align__(16) u16 Ws[2][3 * 64 * 64];    // 2 x 24 KB  (80 KB total)

    const int tid  = threadIdx.x;
    const int lane = tid & 63, wave = tid >> 6;
    const int wm = wave >> 1, wn = wave & 1;          // 2x2 waves: WM=64, WN=32
    const int mbase = blockIdx.y * 128;
    const int nbase = blockIdx.x * 64;
    const int lr = lane & 15;
    const int swkey = lr & 7;                         // row&7 == lr&7 (row bases are x16)

    constexpr int NX = KX / 64;          // x-pass BK64 steps (3 or 16)
    constexpr int NH = R_ / 64;          // h-pass BK64 steps (16)
    constexpr int NT = NX + NH;

    // ---- precomputed staging offsets (loop-invariant; kills per-step VALU) ----
    int offAx[4], offAh[4], offWx[6], offWh[6], ldsA[4], ldsW[6];
#pragma unroll
    for (int p = 0; p < 4; p++) {
        int g = tid + p * 256, row = g >> 3, ch = (g & 7) ^ (row & 7);
        offAx[p] = (mbase + row) * ldax + ch * 8;
        offAh[p] = (mbase + row) * ldah + ch * 8;
        ldsA[p]  = g * 8;
    }
#pragma unroll
    for (int p = 0; p < 6; p++) {
        int q = tid + p * 256, row = q >> 3;
        int gate = row >> 6, rg = row & 63, cw = (q & 7) ^ (row & 7);
        offWx[p] = (gate * R_ + nbase + rg) * KX + cw * 8;
        offWh[p] = (gate * R_ + nbase + rg) * R_ + cw * 8;
        ldsW[p]  = q * 8;
    }
    // fragment read offsets (element units, swizzle key applied at use)
    int aro[4], wro[3][2];
#pragma unroll
    for (int i = 0; i < 4; i++) aro[i] = (wm * 64 + i * 16 + lr) * 64;
#pragma unroll
    for (int g = 0; g < 3; g++)
#pragma unroll
        for (int j = 0; j < 2; j++) wro[g][j] = (g * 64 + wn * 32 + j * 16 + lr) * 64;

    f32x4_t acc_r[4][2], acc_z[4][2], acc_xn[4][2], acc_hn[4][2];
#pragma unroll
    for (int i = 0; i < 4; i++)
#pragma unroll
        for (int j = 0; j < 2; j++) {
            acc_r[i][j]  = (f32x4_t){0,0,0,0};
            acc_z[i][j]  = (f32x4_t){0,0,0,0};
            acc_xn[i][j] = (f32x4_t){0,0,0,0};
            acc_hn[i][j] = (f32x4_t){0,0,0,0};
        }

    // stage BK=64 tile for step s into buffer b: 10 global_load_lds per thread
    auto stage = [&](int s, int b) {
        if (s < NX) {
            const u16* A = Ax + s * 64;
            const u16* W = Wx + s * 64;
#pragma unroll
            for (int p = 0; p < 4; p++) g2l16(A + offAx[p], As[b] + ldsA[p]);
#pragma unroll
            for (int p = 0; p < 6; p++) g2l16(W + offWx[p], Ws[b] + ldsW[p]);
        } else {
            const u16* A = Ah + (s - NX) * 64;
            const u16* W = Wh + (s - NX) * 64;
#pragma unroll
            for (int p = 0; p < 4; p++) g2l16(A + offAh[p], As[b] + ldsA[p]);
#pragma unroll
            for (int p = 0; p < 6; p++) g2l16(W + offWh[p], Ws[b] + ldsW[p]);
        }
    };

    // one tile = 6 phases: (kk=0,1) x (r, z, n). Each phase: ds_read subtile ->
    // barrier -> lgkmcnt(0) -> setprio(1) -> 8 MFMA -> setprio(0) -> barrier.
    auto tile = [&](bool xpass, int b) {
        const u16* Ab = As[b];
        const u16* Wb = Ws[b];
#pragma unroll
        for (int kk = 0; kk < 2; kk++) {
            const int pos = ((kk * 4 + (lane >> 4)) ^ swkey) * 8;
            // ---- phase r: a_f[0..3] + w_r[0..1] ----
            bf16x8_t a_f[4], w0, w1;
#pragma unroll
            for (int i = 0; i < 4; i++) a_f[i] = *(const bf16x8_t*)(Ab + aro[i] + pos);
            w0 = *(const bf16x8_t*)(Wb + wro[0][0] + pos);
            w1 = *(const bf16x8_t*)(Wb + wro[0][1] + pos);
            __builtin_amdgcn_s_barrier();
            asm volatile("s_waitcnt lgkmcnt(0)" ::: "memory");
            __builtin_amdgcn_s_setprio(1);
#pragma unroll
            for (int i = 0; i < 4; i++) {
                acc_r[i][0] = __builtin_amdgcn_mfma_f32_16x16x32_bf16(a_f[i], w0, acc_r[i][0], 0, 0, 0);
                acc_r[i][1] = __builtin_amdgcn_mfma_f32_16x16x32_bf16(a_f[i], w1, acc_r[i][1], 0, 0, 0);
            }
            __builtin_amdgcn_s_setprio(0);
            __builtin_amdgcn_s_barrier();
            // ---- phase z: w_z[0..1] ----
            w0 = *(const bf16x8_t*)(Wb + wro[1][0] + pos);
            w1 = *(const bf16x8_t*)(Wb + wro[1][1] + pos);
            __builtin_amdgcn_s_barrier();
            asm volatile("s_waitcnt lgkmcnt(0)" ::: "memory");
            __builtin_amdgcn_s_setprio(1);
#pragma unroll
            for (int i = 0; i < 4; i++) {
                acc_z[i][0] = __builtin_amdgcn_mfma_f32_16x16x32_bf16(a_f[i], w0, acc_z[i][0], 0, 0, 0);
                acc_z[i][1] = __builtin_amdgcn_mfma_f32_16x16x32_bf16(a_f[i], w1, acc_z[i][1], 0, 0, 0);
            }
            __builtin_amdgcn_s_setprio(0);
            __builtin_amdgcn_s_barrier();
            // ---- phase n: w_n[0..1] ----
            w0 = *(const bf16x8_t*)(Wb + wro[2][0] + pos);
            w1 = *(const bf16x8_t*)(Wb + wro[2][1] + pos);
            __builtin_amdgcn_s_barrier();
            asm volatile("s_waitcnt lgkmcnt(0)" ::: "memory");
            __builtin_amdgcn_s_setprio(1);
            if (xpass) {
#pragma unroll
                for (int i = 0; i < 4; i++) {
                    acc_xn[i][0] = __builtin_amdgcn_mfma_f32_16x16x32_bf16(a_f[i], w0, acc_xn[i][0], 0, 0, 0);
                    acc_xn[i][1] = __builtin_amdgcn_mfma_f32_16x16x32_bf16(a_f[i], w1, acc_xn[i][1], 0, 0, 0);
                }
            } else {
#pragma unroll
                for (int i = 0; i < 4; i++) {
                    acc_hn[i][0] = __builtin_amdgcn_mfma_f32_16x16x32_bf16(a_f[i], w0, acc_hn[i][0], 0, 0, 0);
                    acc_hn[i][1] = __builtin_amdgcn_mfma_f32_16x16x32_bf16(a_f[i], w1, acc_hn[i][1], 0, 0, 0);
                }
            }
            __builtin_amdgcn_s_setprio(0);
            __builtin_amdgcn_s_barrier();
        }
    };

    // ---- main loop: R8's verified counted-vmcnt stage discipline ----
    stage(0, 0);
    stage(1, 1);
#pragma unroll 1
    for (int s = 0; s < NT; ++s) {
        // wait for stage(s)'s 10 loads; stage(s+1)'s 10 stay in flight
        if (s + 1 < NT) asm volatile("s_waitcnt vmcnt(10)" ::: "memory");
        else            asm volatile("s_waitcnt vmcnt(0)" ::: "memory");
        __builtin_amdgcn_s_barrier();            // all waves' stage(s) landed
        tile(s < NX, s & 1);                     // ends with a barrier: buf free
        if (s + 2 < NT) stage(s + 2, s & 1);     // overwrite just-freed buffer
    }

    // ---- epilogue: gates + state update ----
    // C/D layout: col = lane&15, row = (lane>>4)*4 + reg   [HW-verified]
    const int rr2 = (lane >> 4) * 4;
#pragma unroll
    for (int j = 0; j < 2; j++) {
        const int col = nbase + wn * 32 + j * 16 + lr;
        const float b_ir = bi[col],          b_hr = bh[col];
        const float b_iz = bi[R_ + col],     b_hz = bh[R_ + col];
        const float b_in = bi[2 * R_ + col], b_hn = bh[2 * R_ + col];
#pragma unroll
        for (int i = 0; i < 4; i++) {
#pragma unroll
            for (int r = 0; r < 4; r++) {
                const int row = mbase + wm * 64 + i * 16 + rr2 + r;
                const float hold = hf[(size_t)row * R_ + col];
                const float rv = sigmf(acc_r[i][j][r] + b_ir + b_hr);
                const float zv = sigmf(acc_z[i][j][r] + b_iz + b_hz);
                const float nv = tanhfast(acc_xn[i][j][r] + b_in + rv * (acc_hn[i][j][r] + b_hn));
                const float hn = (1.f - zv) * nv + zv * hold;
                hf[(size_t)row * R_ + col] = hn;
                hout[(size_t)row * K2_ + col] = f2bf(hn);
            }
        }
    }
}

// ---------------- FC: 4-way K-split partial GEMM ----------------
// part[kc][B][128] = s12[:, kc*512:(kc+1)*512] @ Wfc[:, same]^T
__global__ __launch_bounds__(256) void fc_part_kernel(
    const u16* __restrict__ A, const u16* __restrict__ W, float* __restrict__ part) {
    __shared__ __align__(16) u16 As[64 * 32];     // 4 KB
    __shared__ __align__(16) u16 Bs[128 * 32];    // 8 KB
    const int tid  = threadIdx.x;
    const int lane = tid & 63, wave = tid >> 6;
    const int wm = wave >> 1, wn = wave & 1;      // WM=32, WN=64
    const int mbase = blockIdx.y * 64;
    const int kbase = blockIdx.x * 512;
    const int lr = lane & 15;
    const int sw = (((lane >> 4) ^ ((lr >> 1) & 3)) * 8);

    f32x4_t acc[2][4];
#pragma unroll
    for (int i = 0; i < 2; i++)
#pragma unroll
        for (int j = 0; j < 4; j++) acc[i][j] = (f32x4_t){0, 0, 0, 0};

    for (int k0 = 0; k0 < 512; k0 += 32) {
        __syncthreads();
        {
            int g = tid;                           // 256 chunks = 64 rows * 4
            int row = g >> 2;
            int ch  = (g & 3) ^ ((row >> 1) & 3);
            g2l16(A + (size_t)(mbase + row) * K2_ + kbase + k0 + ch * 8, As + g * 8);
        }
#pragma unroll
        for (int p = 0; p < 2; p++) {
            int q = tid + p * 256;                 // 512 chunks = 128 rows * 4
            int row = q >> 2;
            int cw  = (q & 3) ^ ((row >> 1) & 3);
            g2l16(W + (size_t)row * K2_ + kbase + k0 + cw * 8, Bs + q * 8);
        }
        __syncthreads();
        bf16x8_t a_f[2], b_f[4];
#pragma unroll
        for (int i = 0; i < 2; i++)
            a_f[i] = *(const bf16x8_t*)(As + (wm * 32 + i * 16 + lr) * 32 + sw);
#pragma unroll
        for (int j = 0; j < 4; j++)
            b_f[j] = *(const bf16x8_t*)(Bs + (wn * 64 + j * 16 + lr) * 32 + sw);
#pragma unroll
        for (int i = 0; i < 2; i++)
#pragma unroll
            for (int j = 0; j < 4; j++)
                acc[i][j] = __builtin_amdgcn_mfma_f32_16x16x32_bf16(a_f[i], b_f[j], acc[i][j], 0, 0, 0);
    }
    const int rr2 = (lane >> 4) * 4;
#pragma unroll
    for (int i = 0; i < 2; i++)
#pragma unroll
        for (int r = 0; r < 4; r++) {
            int row = mbase + wm * 32 + i * 16 + rr2 + r;
#pragma unroll
            for (int j = 0; j < 4; j++) {
                int col = wn * 64 + j * 16 + lr;
                part[((size_t)blockIdx.x * B_ + row) * FCN_ + col] = acc[i][j][r];
            }
        }
}

// out[:, t, :] = prev + sum(4 partials)[:, :67] + bfc  (deterministic reduce)
// FUSED: also builds xpad2 (hi|lo bf16) for decoder step t+1 when write_x != 0.
__global__ void fc_finish_kernel(const float* __restrict__ part, const float* __restrict__ prev,
                                 int pstride, const float* __restrict__ bfc,
                                 float* __restrict__ out, int t,
                                 const float* __restrict__ dec, u16* __restrict__ xpad,
                                 int write_x) {
    int i = blockIdx.x * 256 + threadIdx.x;
    if (i >= B_ * IP_) return;
    int b = i / IP_, c = i % IP_;
    float v = 0.f;
    if (c < H_) {
        size_t idx = (size_t)b * FCN_ + c;
        const size_t S = (size_t)B_ * FCN_;
        float s = (part[idx] + part[S + idx]) + (part[2 * S + idx] + part[3 * S + idx]);
        v = prev[(size_t)b * pstride + c] + s + bfc[c];
        out[((size_t)b * TGT_ + t) * H_ + c] = v;
    } else if (c < I_ && write_x) {
        v = dec[((size_t)b * TGT_ + (t + 1)) * I_ + c];   // next step's action channels
    }
    if (write_x) {
        u16 hi = f2bf(v);
        u16 lo = f2bf(v - bf2f(hi));
        xpad[(size_t)b * IP2_ + c]       = hi;
        xpad[(size_t)b * IP2_ + IP_ + c] = lo;
    }
}

// ---------------- host launcher ----------------
extern "C" void kernel_launch(void* const* d_in, const int* in_sizes, int n_in,
                              void* d_out, int out_size, void* d_ws, size_t ws_size,
                              hipStream_t stream) {
    (void)in_sizes; (void)n_in; (void)out_size; (void)ws_size;
    const float* enc = (const float*)d_in[0];
    const float* dec = (const float*)d_in[1];
    const float* Wi1 = (const float*)d_in[2];
    const float* Wh1 = (const float*)d_in[3];
    const float* bi1 = (const float*)d_in[4];
    const float* bh1 = (const float*)d_in[5];
    const float* Wi2 = (const float*)d_in[6];
    const float* Wh2 = (const float*)d_in[7];
    const float* bi2 = (const float*)d_in[8];
    const float* bh2 = (const float*)d_in[9];
    const float* Wfc = (const float*)d_in[10];
    const float* bfc = (const float*)d_in[11];
    float* out = (float*)d_out;

    char* ws = (char*)d_ws;
    size_t off = 0;
    auto alloc = [&](size_t bytes) -> char* {
        char* p = ws + off;
        off += (bytes + 255) & ~(size_t)255;
        return p;
    };
    u16* Wh1b  = (u16*)alloc((size_t)NG_ * R_ * 2);
    u16* Wi2b  = (u16*)alloc((size_t)NG_ * R_ * 2);
    u16* Wh2b  = (u16*)alloc((size_t)NG_ * R_ * 2);
    u16* Wi1pb = (u16*)alloc((size_t)NG_ * IP2_ * 2);
    u16* Wfcb  = (u16*)alloc((size_t)FCN_ * K2_ * 2);
    // contiguous zero-init group: sbuf0, s1f, s2f
    u16* sbuf0 = (u16*)alloc((size_t)B_ * K2_ * 2);
    float* s1f = (float*)alloc((size_t)B_ * R_ * 4);
    float* s2f = (float*)alloc((size_t)B_ * R_ * 4);
    u16* sbuf1 = (u16*)alloc((size_t)B_ * K2_ * 2);
    u16* xall  = (u16*)alloc((size_t)ENC_STEPS * B_ * IP2_ * 2);
    u16* xpad2 = (u16*)alloc((size_t)B_ * IP2_ * 2);
    float* cfcp = (float*)alloc((size_t)4 * B_ * FCN_ * 4);
    u16* sbuf[2] = { sbuf0, sbuf1 };

    hipMemsetAsync(sbuf0, 0,
                   (size_t)B_ * K2_ * 2 + 2 * (size_t)B_ * R_ * 4, stream);

    // weight prep (rerun every call: ws re-poisoned)
    cast_bf16_kernel<<<(NG_ * R_ + 255) / 256, 256, 0, stream>>>(Wh1, Wh1b, NG_ * R_);
    cast_bf16_kernel<<<(NG_ * R_ + 255) / 256, 256, 0, stream>>>(Wi2, Wi2b, NG_ * R_);
    cast_bf16_kernel<<<(NG_ * R_ + 255) / 256, 256, 0, stream>>>(Wh2, Wh2b, NG_ * R_);
    pad_wi1_dup_kernel<<<(NG_ * IP2_ + 255) / 256, 256, 0, stream>>>(Wi1, Wi1pb);
    pad_wfc_kernel<<<(FCN_ * K2_ + 255) / 256, 256, 0, stream>>>(Wfc, Wfcb);
    pad_all_x_kernel<<<(B_ * ENC_STEPS * IP_ + 255) / 256, 256, 0, stream>>>(enc, xall);

    dim3 gru_grid(R_ / 64, B_ / 128, 1);       // 16 x 32 = 512 blocks (2/CU)
    dim3 fc_grid(4, B_ / 64, 1);               // 256 blocks
    const int binp_blocks = (B_ * IP_ + 255) / 256;
    const int fcf_blocks  = (B_ * IP_ + 255) / 256;   // fused finish covers 96 cols

    int phase = 0;

    // ---------------- encoder: 49 steps ----------------
    for (int t = 0; t < ENC_STEPS; t++) {
        u16* cur = sbuf[phase];
        u16* nxt = sbuf[phase ^ 1];
        gru_step_kernel<IP2_><<<gru_grid, 256, 0, stream>>>(
            xall + (size_t)t * B_ * IP2_, IP2_, Wi1pb,
            cur, K2_, Wh1b, bi1, bh1, s1f, nxt);
        gru_step_kernel<R_><<<gru_grid, 256, 0, stream>>>(
            nxt, K2_, Wi2b,
            cur + R_, K2_, Wh2b, bi2, bh2, s2f, nxt + R_);
        phase ^= 1;
    }

    // ---------------- decoder: 25 steps ----------------
    // initial input from dec[:, 0, :]
    build_inp_kernel<<<binp_blocks, 256, 0, stream>>>(dec, TGT_ * I_, dec, 0, xpad2);
    for (int t = 0; t < TGT_; t++) {
        const float* prev;
        int pstride;
        if (t == 0) { prev = dec;                 pstride = TGT_ * I_; }
        else        { prev = out + (t - 1) * H_;  pstride = TGT_ * H_; }
        u16* cur = sbuf[phase];
        u16* nxt = sbuf[phase ^ 1];
        gru_step_kernel<IP2_><<<gru_grid, 256, 0, stream>>>(
            xpad2, IP2_, Wi1pb,
            cur, K2_, Wh1b, bi1, bh1, s1f, nxt);
        gru_step_kernel<R_><<<gru_grid, 256, 0, stream>>>(
            nxt, K2_, Wi2b,
            cur + R_, K2_, Wh2b, bi2, bh2, s2f, nxt + R_);
        fc_part_kernel<<<fc_grid, 256, 0, stream>>>(nxt, Wfcb, cfcp);
        // fused: writes out[:, t, :] AND xpad2 for step t+1 (skip xpad on last step)
        fc_finish_kernel<<<fcf_blocks, 256, 0, stream>>>(
            cfcp, prev, pstride, bfc, out, t, dec, xpad2, (t < TGT_ - 1) ? 1 : 0);
        phase ^= 1;
    }
}

// Round 10
// 7315.109 us; speedup vs baseline: 2.9610x; 2.9610x over previous
//
#include <hip/hip_runtime.h>
#include <hip/hip_bf16.h>
#include <math.h>

// ---------------- problem constants ----------------
#define B_        4096
#define ENC_STEPS 49     // SRC-1
#define TGT_      25
#define R_        1024
#define H_        67
#define I_        82
#define IP_       96     // input padded to multiple of 32
#define IP2_      192    // split-bf16 (hi|lo) doubled K
#define NG_       3072   // 3*R
#define FCN_      128    // fc output padded 67 -> 128
#define K2_       2048   // 2*R

typedef unsigned short u16;
typedef __attribute__((ext_vector_type(8))) short bf16x8_t;
typedef __attribute__((ext_vector_type(4))) float f32x4_t;

// ---------------- helpers ----------------
__device__ __forceinline__ float bf2f(u16 h) {
    union { unsigned int u; float f; } v; v.u = ((unsigned int)h) << 16; return v.f;
}
__device__ __forceinline__ u16 f2bf(float f) {
    union { unsigned int u; float f; } v; v.f = f;
    unsigned int u = v.u;
    u += 0x7fffu + ((u >> 16) & 1u);   // RNE
    return (u16)(u >> 16);
}
__device__ __forceinline__ float sigmf(float x) { return 1.f / (1.f + __expf(-x)); }
__device__ __forceinline__ float tanhfast(float x) { return 1.f - 2.f / (__expf(2.f * x) + 1.f); }

// async global->LDS, 16B per lane (lane-contiguous linear dest).
__device__ __forceinline__ void g2l16(const u16* g, u16* l) {
    __builtin_amdgcn_global_load_lds(
        (const __attribute__((address_space(1))) unsigned int*)(const void*)g,
        (__attribute__((address_space(3))) unsigned int*)(void*)l,
        16, 0, 0);
}

// ---------------- weight prep ----------------
// Fragment-major W packing: unit = (gate g, 16-col tile ct, 32-k chunk kq);
// element (lane, e): value = W[g*1024 + ct*16 + (lane&15)][kq*32 + (lane>>4)*8 + e].
// A wave's MFMA B-operand load is then ONE coalesced 1KB global_load_dwordx4.
// dst flat index i: e=i&7, lane=(i>>3)&63, kq=(i>>9)%KQ, ct=(i/(512*KQ))%64, g=i/(512*KQ*64).

// pack [3072,1024] fp32 row-major -> fragment-major bf16 (KQ=32)
__global__ void pack_w1024_kernel(const float* __restrict__ s, u16* __restrict__ d) {
    int i = blockIdx.x * 256 + threadIdx.x;
    if (i >= NG_ * R_) return;
    const int KQ = R_ / 32;
    int e = i & 7, lane = (i >> 3) & 63, kq = (i >> 9) % KQ;
    int ct = (i / (512 * KQ)) % 64, g = i / (512 * KQ * 64);
    int row = g * R_ + ct * 16 + (lane & 15);
    int k   = kq * 32 + (lane >> 4) * 8 + e;
    d[i] = f2bf(s[(size_t)row * R_ + k]);
}
// pack Wi1 [3072,82] fp32 -> fragment-major bf16 with pad-to-96 + hi/lo dup (K=192, KQ=6)
__global__ void pack_wi1_kernel(const float* __restrict__ s, u16* __restrict__ d) {
    int i = blockIdx.x * 256 + threadIdx.x;
    if (i >= NG_ * IP2_) return;
    const int KQ = IP2_ / 32;
    int e = i & 7, lane = (i >> 3) & 63, kq = (i >> 9) % KQ;
    int ct = (i / (512 * KQ)) % 64, g = i / (512 * KQ * 64);
    int row = g * R_ + ct * 16 + (lane & 15);
    int k   = kq * 32 + (lane >> 4) * 8 + e;
    int cc  = (k < IP_) ? k : k - IP_;
    d[i] = (cc < I_) ? f2bf(s[(size_t)row * I_ + cc]) : (u16)0;
}
// Wfc [67,2048] -> [128,2048] bf16 row-major (fc_part keeps LDS path)
__global__ void pad_wfc_kernel(const float* __restrict__ s, u16* __restrict__ d) {
    int i = blockIdx.x * 256 + threadIdx.x;
    if (i >= FCN_ * K2_) return;
    int r = i / K2_, c = i % K2_;
    d[i] = (r < H_) ? f2bf(s[(size_t)r * K2_ + c]) : (u16)0;
}

// all encoder inputs -> xall bf16 [ENC][B][192] (hi|lo split), one launch
__global__ void pad_all_x_kernel(const float* __restrict__ enc, u16* __restrict__ xall) {
    int i = blockIdx.x * 256 + threadIdx.x;
    if (i >= B_ * ENC_STEPS * IP_) return;
    int c = i % IP_;
    int t = (i / IP_) % ENC_STEPS;
    int b = i / (IP_ * ENC_STEPS);
    float v = (c < I_) ? enc[((size_t)b * ENC_STEPS + t) * I_ + c] : 0.f;
    u16 hi = f2bf(v);
    u16 lo = f2bf(v - bf2f(hi));
    size_t base = ((size_t)t * B_ + b) * IP2_;
    xall[base + c]       = hi;
    xall[base + IP_ + c] = lo;
}

// decoder inp for t==0 (later steps are fused into fc_finish)
__global__ void build_inp_kernel(const float* __restrict__ prev, int pstride,
                                 const float* __restrict__ dec, int t,
                                 u16* __restrict__ xpad) {
    int i = blockIdx.x * 256 + threadIdx.x;
    if (i >= B_ * IP_) return;
    int b = i / IP_, c = i % IP_;
    float v = 0.f;
    if (c < H_)      v = prev[(size_t)b * pstride + c];
    else if (c < I_) v = dec[((size_t)b * TGT_ + t) * I_ + c];
    u16 hi = f2bf(v);
    u16 lo = f2bf(v - bf2f(hi));
    xpad[(size_t)b * IP2_ + c]       = hi;
    xpad[(size_t)b * IP2_ + IP_ + c] = lo;
}

// ---------------- fused GRU step (one layer) ----------------
// Tile: 128 batch rows x 64 R-cols x 3 gates; 256 threads = 4 waves (2M x 2N);
// 2 blocks/CU. R4's proven single-buffer BK=64 sync structure — but W NEVER
// touches LDS: weights are pre-packed fragment-major, so each B-operand is one
// coalesced 1KB global load issued at loop-top (L2-resident; latency hides
// under the A-stage barrier). LDS holds only the A tile (16 KB). This cuts the
// DS pipe from ~2560 to ~1030 cyc/CU/step; MFMA becomes the critical pipe.
// A staging keeps the verified XOR swizzle (0 conflicts R2-R9).
template<int KX>
__global__ __launch_bounds__(256, 2) void gru_step_kernel(
    const u16* __restrict__ Ax, int ldax,       // [B, ldax] bf16 input
    const u16* __restrict__ Wxp,                // packed [3*64*(KX/32)*512]
    const u16* __restrict__ Ah, int ldah,       // [B, ldah] bf16 state (cur)
    const u16* __restrict__ Whp,                // packed (KQ=32)
    const float* __restrict__ bi, const float* __restrict__ bh,
    float* __restrict__ hf,                     // [B, R] fp32 state, in/out
    u16* __restrict__ hout)                     // bf16 state out, row stride K2_
{
    __shared__ __align__(16) u16 As[128 * 64];       // 16 KB only

    const int tid  = threadIdx.x;
    const int lane = tid & 63, wave = tid >> 6;
    const int wm = wave >> 1, wn = wave & 1;          // 2x2 waves: WM=64, WN=32
    const int mbase = blockIdx.y * 128;
    const int nbase = blockIdx.x * 64;
    const int lr = lane & 15;
    const int swkey = lr & 7;
    const int ctb = (nbase >> 4) + wn * 2;            // this wave's 16-col tile base

    constexpr int NX  = KX / 64;         // x-pass BK64 steps (3 or 16)
    constexpr int NH  = R_ / 64;         // h-pass BK64 steps (16)
    constexpr int KQX = KX / 32;

    f32x4_t acc_r[4][2], acc_z[4][2], acc_xn[4][2], acc_hn[4][2];
#pragma unroll
    for (int i = 0; i < 4; i++)
#pragma unroll
        for (int j = 0; j < 2; j++) {
            acc_r[i][j]  = (f32x4_t){0,0,0,0};
            acc_z[i][j]  = (f32x4_t){0,0,0,0};
            acc_xn[i][j] = (f32x4_t){0,0,0,0};
            acc_hn[i][j] = (f32x4_t){0,0,0,0};
        }

    // ---- x-pass: x @ Wx^T ----
    {
        const u16* wb[6];
#pragma unroll
        for (int g = 0; g < 3; g++)
#pragma unroll
            for (int j = 0; j < 2; j++)
                wb[g * 2 + j] = Wxp + (size_t)((g * 64 + ctb + j) * KQX) * 512 + lane * 8;
#pragma unroll 1
        for (int s = 0; s < NX; s++) {
            bf16x8_t w[2][6];                       // 12 coalesced 1KB loads, issued FIRST
#pragma unroll
            for (int kk = 0; kk < 2; kk++)
#pragma unroll
                for (int u = 0; u < 6; u++)
                    w[kk][u] = *(const bf16x8_t*)(wb[u] + (s * 2 + kk) * 512);
            __syncthreads();                        // prev As reads done
#pragma unroll
            for (int p = 0; p < 4; p++) {           // stage A tile (1024 chunks)
                int g = tid + p * 256, row = g >> 3, ch = (g & 7) ^ (row & 7);
                g2l16(Ax + (size_t)(mbase + row) * ldax + s * 64 + ch * 8, As + g * 8);
            }
            __syncthreads();                        // drains A-DMA (and W loads)
#pragma unroll
            for (int kk = 0; kk < 2; kk++) {
                const int pos = ((kk * 4 + (lane >> 4)) ^ swkey) * 8;
                bf16x8_t a_f[4];
#pragma unroll
                for (int i = 0; i < 4; i++)
                    a_f[i] = *(const bf16x8_t*)(As + (wm * 64 + i * 16 + lr) * 64 + pos);
                __builtin_amdgcn_s_setprio(1);
#pragma unroll
                for (int i = 0; i < 4; i++) {
                    acc_r[i][0]  = __builtin_amdgcn_mfma_f32_16x16x32_bf16(a_f[i], w[kk][0], acc_r[i][0], 0, 0, 0);
                    acc_r[i][1]  = __builtin_amdgcn_mfma_f32_16x16x32_bf16(a_f[i], w[kk][1], acc_r[i][1], 0, 0, 0);
                    acc_z[i][0]  = __builtin_amdgcn_mfma_f32_16x16x32_bf16(a_f[i], w[kk][2], acc_z[i][0], 0, 0, 0);
                    acc_z[i][1]  = __builtin_amdgcn_mfma_f32_16x16x32_bf16(a_f[i], w[kk][3], acc_z[i][1], 0, 0, 0);
                    acc_xn[i][0] = __builtin_amdgcn_mfma_f32_16x16x32_bf16(a_f[i], w[kk][4], acc_xn[i][0], 0, 0, 0);
                    acc_xn[i][1] = __builtin_amdgcn_mfma_f32_16x16x32_bf16(a_f[i], w[kk][5], acc_xn[i][1], 0, 0, 0);
                }
                __builtin_amdgcn_s_setprio(0);
            }
        }
    }
    // ---- h-pass: h_old @ Wh^T ----
    {
        const u16* wb[6];
#pragma unroll
        for (int g = 0; g < 3; g++)
#pragma unroll
            for (int j = 0; j < 2; j++)
                wb[g * 2 + j] = Whp + (size_t)((g * 64 + ctb + j) * 32) * 512 + lane * 8;
#pragma unroll 1
        for (int s = 0; s < NH; s++) {
            bf16x8_t w[2][6];
#pragma unroll
            for (int kk = 0; kk < 2; kk++)
#pragma unroll
                for (int u = 0; u < 6; u++)
                    w[kk][u] = *(const bf16x8_t*)(wb[u] + (s * 2 + kk) * 512);
            __syncthreads();
#pragma unroll
            for (int p = 0; p < 4; p++) {
                int g = tid + p * 256, row = g >> 3, ch = (g & 7) ^ (row & 7);
                g2l16(Ah + (size_t)(mbase + row) * ldah + s * 64 + ch * 8, As + g * 8);
            }
            __syncthreads();
#pragma unroll
            for (int kk = 0; kk < 2; kk++) {
                const int pos = ((kk * 4 + (lane >> 4)) ^ swkey) * 8;
                bf16x8_t a_f[4];
#pragma unroll
                for (int i = 0; i < 4; i++)
                    a_f[i] = *(const bf16x8_t*)(As + (wm * 64 + i * 16 + lr) * 64 + pos);
                __builtin_amdgcn_s_setprio(1);
#pragma unroll
                for (int i = 0; i < 4; i++) {
                    acc_r[i][0]  = __builtin_amdgcn_mfma_f32_16x16x32_bf16(a_f[i], w[kk][0], acc_r[i][0], 0, 0, 0);
                    acc_r[i][1]  = __builtin_amdgcn_mfma_f32_16x16x32_bf16(a_f[i], w[kk][1], acc_r[i][1], 0, 0, 0);
                    acc_z[i][0]  = __builtin_amdgcn_mfma_f32_16x16x32_bf16(a_f[i], w[kk][2], acc_z[i][0], 0, 0, 0);
                    acc_z[i][1]  = __builtin_amdgcn_mfma_f32_16x16x32_bf16(a_f[i], w[kk][3], acc_z[i][1], 0, 0, 0);
                    acc_hn[i][0] = __builtin_amdgcn_mfma_f32_16x16x32_bf16(a_f[i], w[kk][4], acc_hn[i][0], 0, 0, 0);
                    acc_hn[i][1] = __builtin_amdgcn_mfma_f32_16x16x32_bf16(a_f[i], w[kk][5], acc_hn[i][1], 0, 0, 0);
                }
                __builtin_amdgcn_s_setprio(0);
            }
        }
    }

    // ---- epilogue: gates + state update ----
    // C/D layout: col = lane&15, row = (lane>>4)*4 + reg   [HW-verified]
    const int rr2 = (lane >> 4) * 4;
#pragma unroll
    for (int j = 0; j < 2; j++) {
        const int col = nbase + wn * 32 + j * 16 + lr;
        const float b_ir = bi[col],          b_hr = bh[col];
        const float b_iz = bi[R_ + col],     b_hz = bh[R_ + col];
        const float b_in = bi[2 * R_ + col], b_hn = bh[2 * R_ + col];
#pragma unroll
        for (int i = 0; i < 4; i++) {
#pragma unroll
            for (int r = 0; r < 4; r++) {
                const int row = mbase + wm * 64 + i * 16 + rr2 + r;
                const float hold = hf[(size_t)row * R_ + col];
                const float rv = sigmf(acc_r[i][j][r] + b_ir + b_hr);
                const float zv = sigmf(acc_z[i][j][r] + b_iz + b_hz);
                const float nv = tanhfast(acc_xn[i][j][r] + b_in + rv * (acc_hn[i][j][r] + b_hn));
                const float hn = (1.f - zv) * nv + zv * hold;
                hf[(size_t)row * R_ + col] = hn;
                hout[(size_t)row * K2_ + col] = f2bf(hn);
            }
        }
    }
}

// ---------------- FC: 4-way K-split partial GEMM (unchanged, minor cost) ----------------
__global__ __launch_bounds__(256) void fc_part_kernel(
    const u16* __restrict__ A, const u16* __restrict__ W, float* __restrict__ part) {
    __shared__ __align__(16) u16 As[64 * 32];     // 4 KB
    __shared__ __align__(16) u16 Bs[128 * 32];    // 8 KB
    const int tid  = threadIdx.x;
    const int lane = tid & 63, wave = tid >> 6;
    const int wm = wave >> 1, wn = wave & 1;      // WM=32, WN=64
    const int mbase = blockIdx.y * 64;
    const int kbase = blockIdx.x * 512;
    const int lr = lane & 15;
    const int sw = (((lane >> 4) ^ ((lr >> 1) & 3)) * 8);

    f32x4_t acc[2][4];
#pragma unroll
    for (int i = 0; i < 2; i++)
#pragma unroll
        for (int j = 0; j < 4; j++) acc[i][j] = (f32x4_t){0, 0, 0, 0};

    for (int k0 = 0; k0 < 512; k0 += 32) {
        __syncthreads();
        {
            int g = tid;
            int row = g >> 2;
            int ch  = (g & 3) ^ ((row >> 1) & 3);
            g2l16(A + (size_t)(mbase + row) * K2_ + kbase + k0 + ch * 8, As + g * 8);
        }
#pragma unroll
        for (int p = 0; p < 2; p++) {
            int q = tid + p * 256;
            int row = q >> 2;
            int cw  = (q & 3) ^ ((row >> 1) & 3);
            g2l16(W + (size_t)row * K2_ + kbase + k0 + cw * 8, Bs + q * 8);
        }
        __syncthreads();
        bf16x8_t a_f[2], b_f[4];
#pragma unroll
        for (int i = 0; i < 2; i++)
            a_f[i] = *(const bf16x8_t*)(As + (wm * 32 + i * 16 + lr) * 32 + sw);
#pragma unroll
        for (int j = 0; j < 4; j++)
            b_f[j] = *(const bf16x8_t*)(Bs + (wn * 64 + j * 16 + lr) * 32 + sw);
#pragma unroll
        for (int i = 0; i < 2; i++)
#pragma unroll
            for (int j = 0; j < 4; j++)
                acc[i][j] = __builtin_amdgcn_mfma_f32_16x16x32_bf16(a_f[i], b_f[j], acc[i][j], 0, 0, 0);
    }
    const int rr2 = (lane >> 4) * 4;
#pragma unroll
    for (int i = 0; i < 2; i++)
#pragma unroll
        for (int r = 0; r < 4; r++) {
            int row = mbase + wm * 32 + i * 16 + rr2 + r;
#pragma unroll
            for (int j = 0; j < 4; j++) {
                int col = wn * 64 + j * 16 + lr;
                part[((size_t)blockIdx.x * B_ + row) * FCN_ + col] = acc[i][j][r];
            }
        }
}

// out[:, t, :] = prev + sum(4 partials)[:, :67] + bfc; fused xpad build for t+1
__global__ void fc_finish_kernel(const float* __restrict__ part, const float* __restrict__ prev,
                                 int pstride, const float* __restrict__ bfc,
                                 float* __restrict__ out, int t,
                                 const float* __restrict__ dec, u16* __restrict__ xpad,
                                 int write_x) {
    int i = blockIdx.x * 256 + threadIdx.x;
    if (i >= B_ * IP_) return;
    int b = i / IP_, c = i % IP_;
    float v = 0.f;
    if (c < H_) {
        size_t idx = (size_t)b * FCN_ + c;
        const size_t S = (size_t)B_ * FCN_;
        float s = (part[idx] + part[S + idx]) + (part[2 * S + idx] + part[3 * S + idx]);
        v = prev[(size_t)b * pstride + c] + s + bfc[c];
        out[((size_t)b * TGT_ + t) * H_ + c] = v;
    } else if (c < I_ && write_x) {
        v = dec[((size_t)b * TGT_ + (t + 1)) * I_ + c];
    }
    if (write_x) {
        u16 hi = f2bf(v);
        u16 lo = f2bf(v - bf2f(hi));
        xpad[(size_t)b * IP2_ + c]       = hi;
        xpad[(size_t)b * IP2_ + IP_ + c] = lo;
    }
}

// ---------------- host launcher ----------------
extern "C" void kernel_launch(void* const* d_in, const int* in_sizes, int n_in,
                              void* d_out, int out_size, void* d_ws, size_t ws_size,
                              hipStream_t stream) {
    (void)in_sizes; (void)n_in; (void)out_size; (void)ws_size;
    const float* enc = (const float*)d_in[0];
    const float* dec = (const float*)d_in[1];
    const float* Wi1 = (const float*)d_in[2];
    const float* Wh1 = (const float*)d_in[3];
    const float* bi1 = (const float*)d_in[4];
    const float* bh1 = (const float*)d_in[5];
    const float* Wi2 = (const float*)d_in[6];
    const float* Wh2 = (const float*)d_in[7];
    const float* bi2 = (const float*)d_in[8];
    const float* bh2 = (const float*)d_in[9];
    const float* Wfc = (const float*)d_in[10];
    const float* bfc = (const float*)d_in[11];
    float* out = (float*)d_out;

    char* ws = (char*)d_ws;
    size_t off = 0;
    auto alloc = [&](size_t bytes) -> char* {
        char* p = ws + off;
        off += (bytes + 255) & ~(size_t)255;
        return p;
    };
    u16* Wh1p  = (u16*)alloc((size_t)NG_ * R_ * 2);     // packed
    u16* Wi2p  = (u16*)alloc((size_t)NG_ * R_ * 2);     // packed
    u16* Wh2p  = (u16*)alloc((size_t)NG_ * R_ * 2);     // packed
    u16* Wi1p  = (u16*)alloc((size_t)NG_ * IP2_ * 2);   // packed
    u16* Wfcb  = (u16*)alloc((size_t)FCN_ * K2_ * 2);
    // contiguous zero-init group: sbuf0, s1f, s2f
    u16* sbuf0 = (u16*)alloc((size_t)B_ * K2_ * 2);
    float* s1f = (float*)alloc((size_t)B_ * R_ * 4);
    float* s2f = (float*)alloc((size_t)B_ * R_ * 4);
    u16* sbuf1 = (u16*)alloc((size_t)B_ * K2_ * 2);
    u16* xall  = (u16*)alloc((size_t)ENC_STEPS * B_ * IP2_ * 2);
    u16* xpad2 = (u16*)alloc((size_t)B_ * IP2_ * 2);
    float* cfcp = (float*)alloc((size_t)4 * B_ * FCN_ * 4);
    u16* sbuf[2] = { sbuf0, sbuf1 };

    hipMemsetAsync(sbuf0, 0,
                   (size_t)B_ * K2_ * 2 + 2 * (size_t)B_ * R_ * 4, stream);

    // weight prep: pack into MFMA-fragment-major order (rerun every call)
    pack_w1024_kernel<<<(NG_ * R_ + 255) / 256, 256, 0, stream>>>(Wh1, Wh1p);
    pack_w1024_kernel<<<(NG_ * R_ + 255) / 256, 256, 0, stream>>>(Wi2, Wi2p);
    pack_w1024_kernel<<<(NG_ * R_ + 255) / 256, 256, 0, stream>>>(Wh2, Wh2p);
    pack_wi1_kernel<<<(NG_ * IP2_ + 255) / 256, 256, 0, stream>>>(Wi1, Wi1p);
    pad_wfc_kernel<<<(FCN_ * K2_ + 255) / 256, 256, 0, stream>>>(Wfc, Wfcb);
    pad_all_x_kernel<<<(B_ * ENC_STEPS * IP_ + 255) / 256, 256, 0, stream>>>(enc, xall);

    dim3 gru_grid(R_ / 64, B_ / 128, 1);       // 16 x 32 = 512 blocks (2/CU)
    dim3 fc_grid(4, B_ / 64, 1);               // 256 blocks
    const int binp_blocks = (B_ * IP_ + 255) / 256;
    const int fcf_blocks  = (B_ * IP_ + 255) / 256;

    int phase = 0;

    // ---------------- encoder: 49 steps ----------------
    for (int t = 0; t < ENC_STEPS; t++) {
        u16* cur = sbuf[phase];
        u16* nxt = sbuf[phase ^ 1];
        gru_step_kernel<IP2_><<<gru_grid, 256, 0, stream>>>(
            xall + (size_t)t * B_ * IP2_, IP2_, Wi1p,
            cur, K2_, Wh1p, bi1, bh1, s1f, nxt);
        gru_step_kernel<R_><<<gru_grid, 256, 0, stream>>>(
            nxt, K2_, Wi2p,
            cur + R_, K2_, Wh2p, bi2, bh2, s2f, nxt + R_);
        phase ^= 1;
    }

    // ---------------- decoder: 25 steps ----------------
    build_inp_kernel<<<binp_blocks, 256, 0, stream>>>(dec, TGT_ * I_, dec, 0, xpad2);
    for (int t = 0; t < TGT_; t++) {
        const float* prev;
        int pstride;
        if (t == 0) { prev = dec;                 pstride = TGT_ * I_; }
        else        { prev = out + (t - 1) * H_;  pstride = TGT_ * H_; }
        u16* cur = sbuf[phase];
        u16* nxt = sbuf[phase ^ 1];
        gru_step_kernel<IP2_><<<gru_grid, 256, 0, stream>>>(
            xpad2, IP2_, Wi1p,
            cur, K2_, Wh1p, bi1, bh1, s1f, nxt);
        gru_step_kernel<R_><<<gru_grid, 256, 0, stream>>>(
            nxt, K2_, Wi2p,
            cur + R_, K2_, Wh2p, bi2, bh2, s2f, nxt + R_);
        fc_part_kernel<<<fc_grid, 256, 0, stream>>>(nxt, Wfcb, cfcp);
        fc_finish_kernel<<<fcf_blocks, 256, 0, stream>>>(
            cfcp, prev, pstride, bfc, out, t, dec, xpad2, (t < TGT_ - 1) ? 1 : 0);
        phase ^= 1;
    }
}